// Round 15
// baseline (101.114 us; speedup 1.0000x reference)
//
#include <hip/hip_runtime.h>
#include <float.h>
#include <math.h>

// Detect (SSD post-processing) — R25: R24/R21 base + ONE isolated change:
// FOLDED HISTOGRAM — bucket atomicAdd moves into the compaction pass-branch
// (~3 passing lanes/wave-round, negligible contention); deletes the separate
// 437-element histogram pass + one barrier. (R13/R14 bundled this with the
// regressing 9-deep burst; R22 isolated the burst as poison; this isolates
// the histogram fold on the proven depth-2 compaction.)
// Structure otherwise exact R21: one block per (b,cls), 168 x 1024;
// depth-2 pipelined compaction; bucket sort (>>14) with rank+gather fusion;
// kcap=4 lazy k-extent + full-recompute fallback; role-split rounds
// (wave 0 scans chunk c, waves 1-15 build chunk c+1); early exit at 200.
// Exact ref semantics: pass > 0.95; stable top-600 (score desc, idx asc);
// IEEE-div IoU > 0.45; slots >= n get (0, box[first passing]); empty zeros.

#define P_PRIORS  8732
#define C_CLASSES 21
#define B_BATCH   8
#define TOPK      200
#define MCAND     600
#define CONF_T    0.95f
#define NMS_T     0.45f
#define NB        64           // score buckets
#define MINB      0x3F733334u  // bits of smallest float > 0.95f
#define KCAP      4            // lazy k-extent: covers mstop <= 256

__device__ __forceinline__ uint64_t pack_key(float sc, int p) {
    return ((uint64_t)__float_as_uint(sc) << 32) | (uint32_t)(~(uint32_t)p);
}
__device__ __forceinline__ int bucket_of(uint64_t key) {
    unsigned d = (unsigned)(key >> 32) - MINB;   // >= 0 since score > 0.95
    int b = (int)(d >> 14);                      // span 0xCCCCC -> ~51 buckets
    return b < (NB - 1) ? b : (NB - 1);
}

#define IOU_ROW(BI, AI, MW, DIAG) do {                                   \
    float xx1 = fmaxf((BI).x, bj.x);                                     \
    float yy1 = fmaxf((BI).y, bj.y);                                     \
    float xx2 = fminf((BI).z, bj.z);                                     \
    float yy2 = fminf((BI).w, bj.w);                                     \
    float ww  = fmaxf(xx2 - xx1, 0.0f);                                  \
    float hh  = fmaxf(yy2 - yy1, 0.0f);                                  \
    float inter = ww * hh;                                               \
    float den   = ((AI) + aj) - inter;   /* ref assoc order */           \
    float iou   = inter / den;           /* IEEE div (matches ref) */    \
    uint64_t m = __ballot(iou > NMS_T);                                  \
    if (k == c) m &= (DIAG);                                             \
    (MW) = (lid == k) ? m : (MW);                                        \
} while (0)

// 16-wave chunk builder (prologue): wave wid handles rows c*64+wid+{0,16,32,48}
__device__ __forceinline__ void iou_chunk16(
    int c, int wid, int lid, int M, int kend,
    const float4* s_jb, const float* s_area, uint64_t* s_bm)
{
    const int i0 = (c << 6) + wid;
    const float4 b0 = s_jb[i0],      b1 = s_jb[i0 + 16],
                 b2 = s_jb[i0 + 32], b3 = s_jb[i0 + 48];
    const float  a0 = s_area[i0],      a1 = s_area[i0 + 16],
                 a2 = s_area[i0 + 32], a3 = s_area[i0 + 48];
    const uint64_t d0 = ~0ull << (wid + 1);
    const uint64_t d1 = ~0ull << (wid + 17);
    const uint64_t d2 = ~0ull << (wid + 33);
    const uint64_t d3 = (wid == 15) ? 0ull : (~0ull << (wid + 49));
    uint64_t w0 = 0, w1 = 0, w2 = 0, w3 = 0;
    for (int k = c; k < kend; ++k) {
        const float4 bj = s_jb[(k << 6) + lid];
        const float  aj = s_area[(k << 6) + lid];
        IOU_ROW(b0, a0, w0, d0);
        IOU_ROW(b1, a1, w1, d1);
        IOU_ROW(b2, a2, w2, d2);
        IOU_ROW(b3, a3, w3, d3);
    }
    if (lid >= c && lid < kend) {
        if (i0      < M) s_bm[(size_t)(i0     ) * 10 + lid] = w0;
        if (i0 + 16 < M) s_bm[(size_t)(i0 + 16) * 10 + lid] = w1;
        if (i0 + 32 < M) s_bm[(size_t)(i0 + 32) * 10 + lid] = w2;
        if (i0 + 48 < M) s_bm[(size_t)(i0 + 48) * 10 + lid] = w3;
    }
}

// 15-wave chunk builder (rounds): wave w (1..15) handles rows
// c*64+{w-1, w+14, w+29, w+44} and, for w<=4, also row c*64+59+w.
__device__ __forceinline__ void iou_rows15(
    int c, int w15, int lid, int M, int kend,
    const float4* s_jb, const float* s_area, uint64_t* s_bm)
{
    const int base = (c << 6);
    const int r0 = base + (w15 - 1);
    const int r1 = r0 + 15, r2 = r0 + 30, r3 = r0 + 45;
    const bool has5 = (w15 <= 4);               // wave-uniform
    const int r4 = base + 59 + w15;             // valid iff has5
    const float4 b0 = s_jb[r0], b1 = s_jb[r1], b2 = s_jb[r2], b3 = s_jb[r3];
    const float  a0 = s_area[r0], a1 = s_area[r1], a2 = s_area[r2], a3 = s_area[r3];
    const float4 b4 = s_jb[has5 ? r4 : r0];
    const float  a4 = s_area[has5 ? r4 : r0];
    const uint64_t d0 = ~0ull << (w15);
    const uint64_t d1 = ~0ull << (w15 + 15);
    const uint64_t d2 = ~0ull << (w15 + 30);
    const uint64_t d3 = ~0ull << (w15 + 45);    // <= 60, safe
    const uint64_t d4 = (59 + w15 == 63) ? 0ull : (~0ull << (60 + w15));
    uint64_t w0 = 0, w1 = 0, w2 = 0, w3 = 0, w4 = 0;
    for (int k = c; k < kend; ++k) {
        const float4 bj = s_jb[(k << 6) + lid]; // ONE column load feeds 4-5 rows
        const float  aj = s_area[(k << 6) + lid];
        IOU_ROW(b0, a0, w0, d0);
        IOU_ROW(b1, a1, w1, d1);
        IOU_ROW(b2, a2, w2, d2);
        IOU_ROW(b3, a3, w3, d3);
        if (has5) { IOU_ROW(b4, a4, w4, d4); }
    }
    if (lid >= c && lid < kend) {
        if (r0 < M) s_bm[(size_t)r0 * 10 + lid] = w0;
        if (r1 < M) s_bm[(size_t)r1 * 10 + lid] = w1;
        if (r2 < M) s_bm[(size_t)r2 * 10 + lid] = w2;
        if (r3 < M) s_bm[(size_t)r3 * 10 + lid] = w3;
        if (has5 && r4 < M) s_bm[(size_t)r4 * 10 + lid] = w4;
    }
}

// ====================== detect_one: 168 x 1024, fully fused ======================
__global__ __launch_bounds__(1024) void detect_one(
    const float* __restrict__ loc, const float* __restrict__ conf,
    float* __restrict__ out)
{
    // XCD swizzle: batch = blockIdx&7 -> all 21 class-blocks of a batch on one L2.
    const int b   = blockIdx.x & 7;
    const int cls = blockIdx.x >> 3;         // 0..20
    const int tid = threadIdx.x;
    float* o = out + ((size_t)(b * C_CLASSES + cls)) * TOPK * 5;

    if (cls == 0) {                           // background: zeros
        for (int k = tid; k < TOPK * 5; k += 1024) o[k] = 0.0f;
        return;
    }

    const float*  confb = conf + (size_t)b * P_PRIORS * C_CLASSES + cls;
    const float4* loc4  = (const float4*)(loc + (size_t)b * P_PRIORS * 4);

    // s_bm (48 KB) phase-aliased: [0,1024) raw keys | [1024,2048) grouped |
    // finally bitmask rows [i*10+k] (key data dead after rank)
    __shared__ uint64_t s_bm[MCAND * 10];
    __shared__ float4   s_jb[640];
    __shared__ float    s_area[640];
    __shared__ float    s_ssc[MCAND];
    __shared__ int      s_bcnt[NB], s_bcur[NB], s_boff[NB];
    __shared__ int      s_cnt, s_fp;
    __shared__ uint64_t s_suppw[10], s_keepw[10];
    __shared__ int      s_prefix[10], s_n, s_mstop, s_done;

    uint64_t* s_k = s_bm;                   // raw keys
    uint64_t* s_g = s_bm + 1024;            // grouped by bucket

    if (tid < NB)                    s_bcnt[tid] = 0;
    else if (tid < 2 * NB)           s_bcur[tid - NB] = 0;
    else if (tid == 2 * NB)        { s_cnt = 0; s_fp = 0x7FFFFFFF; }
    __syncthreads();

    // ---- 1. compact own column: DEPTH-2 PIPELINED loads, ballot push,
    //         FOLDED histogram (bucket count at key-write time) ----
    {
        const int lid = tid & 63;
        float vcur  = confb[(size_t)tid * C_CLASSES];
        float vnext = confb[(size_t)(tid + 1024) * C_CLASSES];
        #pragma unroll
        for (int r = 0; r < 9; ++r) {
            float v = vcur;
            vcur = vnext;
            // issue load r+2 (2 in flight max); r+2==8 is the guarded tail
            if (r + 2 <= 7) {
                vnext = confb[(size_t)(tid + ((r + 2) << 10)) * C_CLASSES];
            } else if (r + 2 == 8) {
                int pn = tid + 8192;
                vnext = (pn < P_PRIORS) ? confb[(size_t)pn * C_CLASSES] : 0.0f;
            } else {
                vnext = 0.0f;
            }
            int p = tid + (r << 10);
            bool pass = v > CONF_T;          // OOB tail loaded as 0.0f -> false
            uint64_t mask = __ballot(pass);
            if (mask != 0) {
                int leader = (int)__ffsll((unsigned long long)mask) - 1;
                int base = 0;
                if (lid == leader) {
                    base = atomicAdd(&s_cnt, __popcll(mask));  // 1 atomic/wave
                    atomicMin(&s_fp, p);     // leader = lowest lane = lowest p
                }
                base = __shfl(base, leader, 64);
                if (pass) {
                    int pos = base + __popcll(mask & ((1ull << lid) - 1ull));
                    if (pos < 1024) {
                        uint64_t key = pack_key(v, p);
                        s_k[pos] = key;
                        atomicAdd(&s_bcnt[bucket_of(key)], 1);  // folded histogram
                    }
                }
            }
        }
    }
    __syncthreads();
    int cnt = s_cnt; if (cnt > 1024) cnt = 1024;
    if (cnt == 0) {
        for (int k = tid; k < TOPK * 5; k += 1024) o[k] = 0.0f;
        return;
    }

    // ---- 2a. bucket offsets: wave-0 reversed shuffle scan ----
    if (tid < 64) {
        int c = s_bcnt[63 - tid];
        int incl = c;
        #pragma unroll
        for (int d = 1; d < 64; d <<= 1) {
            int u = __shfl_up(incl, d, 64);
            if (tid >= d) incl += u;
        }
        s_boff[63 - tid] = incl - c;        // sum of counts of buckets > bb
    }
    __syncthreads();

    // ---- 2b. scatter grouped-by-bucket ----
    for (int t = tid; t < cnt; t += 1024) {
        uint64_t kt = s_k[t];
        int bb = bucket_of(kt);
        s_g[s_boff[bb] + atomicAdd(&s_bcur[bb], 1)] = kt;
    }
    __syncthreads();

    // ---- 2c. WAVE-PER-BUCKET rank FUSED with gather: write score/box/area
    // at rank r directly (keys unique => ranks unique => exact stable order).
    const int M = cnt < MCAND ? cnt : MCAND;
    {
        const int wid = tid >> 6, lid = tid & 63;
        for (int bb = wid; bb < NB; bb += 16) {
            int st = s_boff[bb], n = s_bcnt[bb];
            for (int e = lid; e < n; e += 64) {
                uint64_t kq = s_g[st + e];
                int r = st;
                for (int q = 0; q < n; ++q)
                    r += (s_g[st + q] > kq) ? 1 : 0;   // same addr all lanes
                if (r < MCAND) {
                    int p = (int)(~(uint32_t)kq);
                    s_ssc[r]  = __uint_as_float((uint32_t)(kq >> 32));
                    float4 bx = loc4[p];               // hidden under rank loop
                    s_jb[r]   = bx;
                    s_area[r] = (bx.z - bx.x) * (bx.w - bx.y);
                }
            }
        }
    }
    // pad region (independent of rank writes)
    for (int i = M + tid; i < 640; i += 1024) {
        s_jb[i]   = make_float4(INFINITY, INFINITY, INFINITY, INFINITY);
        s_area[i] = INFINITY;
    }
    const int fp = s_fp;
    __syncthreads();                        // key data dead; s_bm -> bitmask

    const int kmax = (M + 63) >> 6;
    const int kcap = kmax < KCAP ? kmax : KCAP; // words consumed when mstop<=256

    // ---- 3+4. ROLE-SPLIT rounds: wave 0 scans chunk c; waves 1-15 build
    // chunk c+1. Round wall = max(scan, iou). Early exit at 200 keeps.
    // Only words [c, kcap) computed: supp words >= kcap accumulate garbage but
    // are consumed only if mstop > 64*kcap -> handled by the fallback below.
    {
        const int wid = tid >> 6, lid = tid & 63;
        const int w   = (lid < 10) ? lid : 0;         // wave-0 word slot
        uint64_t supp = 0;
        int kept = 0, mstop = M;
        const int nch = kcap;               // scannable chunks (rows < 64*kcap)

        iou_chunk16(0, wid, lid, M, kcap, s_jb, s_area, s_bm);  // 16-wave prologue
        __syncthreads();

        for (int c = 0; c < nch; ++c) {
            if (wid == 0) {
                // ---- scan chunk c (serial, 8-ahead LDS prefetch) ----
                const int ibeg = c << 6;
                const int iend = min(ibeg + 64, M);
                uint64_t rb[8];
                #pragma unroll
                for (int d = 0; d < 8; ++d) {
                    int i = ibeg + d;
                    rb[d] = (i < iend) ? s_bm[(size_t)i * 10 + w] : 0;
                }
                for (int i = ibeg; i < iend; ++i) {
                    uint64_t row = rb[i & 7];
                    if (w < c) row = 0;               // sub-diagonal words unwritten
                    int ip = i + 8;
                    rb[i & 7] = (ip < iend) ? s_bm[(size_t)ip * 10 + w] : 0;
                    bool mybit = (w == c) && ((supp >> (i & 63)) & 1ull);
                    if (!__any((int)mybit)) {         // not suppressed -> keep
                        supp |= row;
                        if (++kept == TOPK) { mstop = i + 1; break; }
                    }
                }
                if (lid == 0) s_done = (kept >= TOPK) ? 1 : 0;
            } else if (c + 1 < nch) {
                iou_rows15(c + 1, wid, lid, M, kcap, s_jb, s_area, s_bm);
            }
            __syncthreads();
            if (s_done) break;                        // uniform after barrier
        }
        if (wid == 0) {
            if (lid < 10) s_suppw[lid] = supp;
            if (lid == 0) s_mstop = mstop;
        }
    }
    __syncthreads();

    // ---- 4b. RARE fallback: scan exhausted rows < 64*kcap with kept < 200
    // and M beyond -> full-extent recompute + full rescan (never on this data).
    if (s_done == 0 && M > (KCAP << 6)) {
        const int wid = tid >> 6, lid = tid & 63;
        for (int i = wid; i < M; i += 16) {
            float4 bi = s_jb[i];
            float  ai = s_area[i];
            const int k0 = i >> 6;
            uint64_t diag = ((i & 63) == 63) ? 0ull : (~0ull << ((i & 63) + 1));
            uint64_t myw = 0;
            for (int k = k0; k < kmax; ++k) {
                float4 bj = s_jb[(k << 6) + lid];
                float  aj = s_area[(k << 6) + lid];
                float xx1 = fmaxf(bi.x, bj.x);
                float yy1 = fmaxf(bi.y, bj.y);
                float xx2 = fminf(bi.z, bj.z);
                float yy2 = fminf(bi.w, bj.w);
                float ww  = fmaxf(xx2 - xx1, 0.0f);
                float hh  = fmaxf(yy2 - yy1, 0.0f);
                float inter = ww * hh;
                float den   = (ai + aj) - inter;
                float iou   = inter / den;
                uint64_t m = __ballot(iou > NMS_T);
                if (k == k0) m &= diag;
                myw = (lid == k) ? m : myw;
            }
            if (lid >= k0 && lid < kmax) s_bm[(size_t)i * 10 + lid] = myw;
        }
        __syncthreads();
        if (tid < 64) {                     // full serial rescan (proven form)
            const int w = (tid < 10) ? tid : 0;
            uint64_t supp = 0;
            int kept = 0, ms = M;
            for (int i = 0; i < M; ++i) {
                uint64_t row = s_bm[(size_t)i * 10 + w];
                if (w < (i >> 6)) row = 0;
                unsigned part  = (unsigned)(supp >> (i & 32));
                unsigned wordv = (unsigned)__builtin_amdgcn_readlane((int)part, i >> 6);
                if (!((wordv >> (i & 31)) & 1u)) {
                    supp |= row;
                    if (++kept == TOPK) { ms = i + 1; break; }
                }
            }
            if (tid < 10) s_suppw[tid] = supp;
            if (tid == 0) s_mstop = ms;
        }
        __syncthreads();
    }

    if (tid == 0) {
        const int Me = s_mstop;
        int total = 0;
        for (int w = 0; w < 10; ++w) {
            uint64_t kw = 0;
            int rem = Me - (w << 6);
            if (rem > 0) {
                uint64_t vm = (rem >= 64) ? ~0ull : ((1ull << rem) - 1ull);
                kw = (~s_suppw[w]) & vm;
            }
            s_keepw[w]  = kw;
            s_prefix[w] = total;
            total += __popcll(kw);
        }
        s_n = total < TOPK ? total : TOPK;
    }
    __syncthreads();

    // ---- 5. output ----
    const int n  = s_n;
    const int Me = s_mstop;
    float4 fbox = loc4[fp];
    for (int k = tid; k < TOPK; k += 1024) {
        if (k >= n) {
            o[k * 5 + 0] = 0.0f;
            o[k * 5 + 1] = fbox.x; o[k * 5 + 2] = fbox.y;
            o[k * 5 + 3] = fbox.z; o[k * 5 + 4] = fbox.w;
        }
    }
    for (int t = tid; t < Me; t += 1024) {
        uint64_t kw = s_keepw[t >> 6];
        if ((kw >> (t & 63)) & 1ull) {
            int r = s_prefix[t >> 6] + __popcll(kw & ((1ull << (t & 63)) - 1ull));
            if (r < TOPK) {
                float4 bx = s_jb[t];
                o[r * 5 + 0] = s_ssc[t];
                o[r * 5 + 1] = bx.x; o[r * 5 + 2] = bx.y;
                o[r * 5 + 3] = bx.z; o[r * 5 + 4] = bx.w;
            }
        }
    }
}

extern "C" void kernel_launch(void* const* d_in, const int* in_sizes, int n_in,
                              void* d_out, int out_size, void* d_ws, size_t ws_size,
                              hipStream_t stream) {
    const float* loc  = (const float*)d_in[0];   // [8, 8732, 4]
    const float* conf = (const float*)d_in[1];   // [8, 8732, 21]
    float* out = (float*)d_out;                  // [8, 21, 200, 5]
    (void)d_ws; (void)ws_size;

    detect_one<<<dim3(B_BATCH * C_CLASSES), dim3(1024), 0, stream>>>(loc, conf, out);
}

// Round 16
// 100.260 us; speedup vs baseline: 1.0085x; 1.0085x over previous
//
#include <hip/hip_runtime.h>
#include <float.h>
#include <math.h>

// Detect (SSD post-processing) — R26 = FINAL: exact R24/R21 hold (session
// best, measured 100.47 us total / 45.5-46.4 us kernel; third replication).
// Session ledger — wins (all critical-path work/phase removal): chunked lazy
// IoU + overlapped scan (-18us), single-kernel fusion (-4), kcap lazy
// k-extent (-4.4), role-split rounds (-2), rank+gather fusion + kcap=4 (-3).
// Poisons (reverted): 9-deep burst loads (L1/L2 queue flood, +7.5), paired
// rounds (longer serial head, +6), flat rank sort (LDS issue volume, +6).
// Neutral: IoU depth-2 prefetch, readlane scan, folded histogram.
// Structure: one block per (b,cls), 168 x 1024.
//  - depth-2 pipelined compaction loads + wave-aggregated ballot push
//  - bucket sort (>>14 spread) with rank+gather FUSION (keys unique =>
//    exact stable order: score desc, idx asc)
//  - kcap=4 lazy k-extent (scan consumes words <=3 when mstop<=256;
//    full-recompute fallback for any other distribution)
//  - ROLE-SPLIT rounds: wave 0 scans chunk c; waves 1-15 build chunk c+1;
//    16-wave prologue builds chunk 0; early exit at 200 keeps
// Exact ref semantics: pass > 0.95; stable top-600; IEEE-div IoU > 0.45;
// slots >= n get (0, box[first passing]); empty zeros.

#define P_PRIORS  8732
#define C_CLASSES 21
#define B_BATCH   8
#define TOPK      200
#define MCAND     600
#define CONF_T    0.95f
#define NMS_T     0.45f
#define NB        64           // score buckets
#define MINB      0x3F733334u  // bits of smallest float > 0.95f
#define KCAP      4            // lazy k-extent: covers mstop <= 256

__device__ __forceinline__ uint64_t pack_key(float sc, int p) {
    return ((uint64_t)__float_as_uint(sc) << 32) | (uint32_t)(~(uint32_t)p);
}
__device__ __forceinline__ int bucket_of(uint64_t key) {
    unsigned d = (unsigned)(key >> 32) - MINB;   // >= 0 since score > 0.95
    int b = (int)(d >> 14);                      // span 0xCCCCC -> ~51 buckets
    return b < (NB - 1) ? b : (NB - 1);
}

#define IOU_ROW(BI, AI, MW, DIAG) do {                                   \
    float xx1 = fmaxf((BI).x, bj.x);                                     \
    float yy1 = fmaxf((BI).y, bj.y);                                     \
    float xx2 = fminf((BI).z, bj.z);                                     \
    float yy2 = fminf((BI).w, bj.w);                                     \
    float ww  = fmaxf(xx2 - xx1, 0.0f);                                  \
    float hh  = fmaxf(yy2 - yy1, 0.0f);                                  \
    float inter = ww * hh;                                               \
    float den   = ((AI) + aj) - inter;   /* ref assoc order */           \
    float iou   = inter / den;           /* IEEE div (matches ref) */    \
    uint64_t m = __ballot(iou > NMS_T);                                  \
    if (k == c) m &= (DIAG);                                             \
    (MW) = (lid == k) ? m : (MW);                                        \
} while (0)

// 16-wave chunk builder (prologue): wave wid handles rows c*64+wid+{0,16,32,48}
__device__ __forceinline__ void iou_chunk16(
    int c, int wid, int lid, int M, int kend,
    const float4* s_jb, const float* s_area, uint64_t* s_bm)
{
    const int i0 = (c << 6) + wid;
    const float4 b0 = s_jb[i0],      b1 = s_jb[i0 + 16],
                 b2 = s_jb[i0 + 32], b3 = s_jb[i0 + 48];
    const float  a0 = s_area[i0],      a1 = s_area[i0 + 16],
                 a2 = s_area[i0 + 32], a3 = s_area[i0 + 48];
    const uint64_t d0 = ~0ull << (wid + 1);
    const uint64_t d1 = ~0ull << (wid + 17);
    const uint64_t d2 = ~0ull << (wid + 33);
    const uint64_t d3 = (wid == 15) ? 0ull : (~0ull << (wid + 49));
    uint64_t w0 = 0, w1 = 0, w2 = 0, w3 = 0;
    for (int k = c; k < kend; ++k) {
        const float4 bj = s_jb[(k << 6) + lid];
        const float  aj = s_area[(k << 6) + lid];
        IOU_ROW(b0, a0, w0, d0);
        IOU_ROW(b1, a1, w1, d1);
        IOU_ROW(b2, a2, w2, d2);
        IOU_ROW(b3, a3, w3, d3);
    }
    if (lid >= c && lid < kend) {
        if (i0      < M) s_bm[(size_t)(i0     ) * 10 + lid] = w0;
        if (i0 + 16 < M) s_bm[(size_t)(i0 + 16) * 10 + lid] = w1;
        if (i0 + 32 < M) s_bm[(size_t)(i0 + 32) * 10 + lid] = w2;
        if (i0 + 48 < M) s_bm[(size_t)(i0 + 48) * 10 + lid] = w3;
    }
}

// 15-wave chunk builder (rounds): wave w (1..15) handles rows
// c*64+{w-1, w+14, w+29, w+44} and, for w<=4, also row c*64+59+w.
__device__ __forceinline__ void iou_rows15(
    int c, int w15, int lid, int M, int kend,
    const float4* s_jb, const float* s_area, uint64_t* s_bm)
{
    const int base = (c << 6);
    const int r0 = base + (w15 - 1);
    const int r1 = r0 + 15, r2 = r0 + 30, r3 = r0 + 45;
    const bool has5 = (w15 <= 4);               // wave-uniform
    const int r4 = base + 59 + w15;             // valid iff has5
    const float4 b0 = s_jb[r0], b1 = s_jb[r1], b2 = s_jb[r2], b3 = s_jb[r3];
    const float  a0 = s_area[r0], a1 = s_area[r1], a2 = s_area[r2], a3 = s_area[r3];
    const float4 b4 = s_jb[has5 ? r4 : r0];
    const float  a4 = s_area[has5 ? r4 : r0];
    const uint64_t d0 = ~0ull << (w15);
    const uint64_t d1 = ~0ull << (w15 + 15);
    const uint64_t d2 = ~0ull << (w15 + 30);
    const uint64_t d3 = ~0ull << (w15 + 45);    // <= 60, safe
    const uint64_t d4 = (59 + w15 == 63) ? 0ull : (~0ull << (60 + w15));
    uint64_t w0 = 0, w1 = 0, w2 = 0, w3 = 0, w4 = 0;
    for (int k = c; k < kend; ++k) {
        const float4 bj = s_jb[(k << 6) + lid]; // ONE column load feeds 4-5 rows
        const float  aj = s_area[(k << 6) + lid];
        IOU_ROW(b0, a0, w0, d0);
        IOU_ROW(b1, a1, w1, d1);
        IOU_ROW(b2, a2, w2, d2);
        IOU_ROW(b3, a3, w3, d3);
        if (has5) { IOU_ROW(b4, a4, w4, d4); }
    }
    if (lid >= c && lid < kend) {
        if (r0 < M) s_bm[(size_t)r0 * 10 + lid] = w0;
        if (r1 < M) s_bm[(size_t)r1 * 10 + lid] = w1;
        if (r2 < M) s_bm[(size_t)r2 * 10 + lid] = w2;
        if (r3 < M) s_bm[(size_t)r3 * 10 + lid] = w3;
        if (has5 && r4 < M) s_bm[(size_t)r4 * 10 + lid] = w4;
    }
}

// ====================== detect_one: 168 x 1024, fully fused ======================
__global__ __launch_bounds__(1024) void detect_one(
    const float* __restrict__ loc, const float* __restrict__ conf,
    float* __restrict__ out)
{
    // XCD swizzle: batch = blockIdx&7 -> all 21 class-blocks of a batch on one L2.
    const int b   = blockIdx.x & 7;
    const int cls = blockIdx.x >> 3;         // 0..20
    const int tid = threadIdx.x;
    float* o = out + ((size_t)(b * C_CLASSES + cls)) * TOPK * 5;

    if (cls == 0) {                           // background: zeros
        for (int k = tid; k < TOPK * 5; k += 1024) o[k] = 0.0f;
        return;
    }

    const float*  confb = conf + (size_t)b * P_PRIORS * C_CLASSES + cls;
    const float4* loc4  = (const float4*)(loc + (size_t)b * P_PRIORS * 4);

    // s_bm (48 KB) phase-aliased: [0,1024) raw keys | [1024,2048) grouped |
    // finally bitmask rows [i*10+k] (key data dead after rank)
    __shared__ uint64_t s_bm[MCAND * 10];
    __shared__ float4   s_jb[640];
    __shared__ float    s_area[640];
    __shared__ float    s_ssc[MCAND];
    __shared__ int      s_bcnt[NB], s_bcur[NB], s_boff[NB];
    __shared__ int      s_cnt, s_fp;
    __shared__ uint64_t s_suppw[10], s_keepw[10];
    __shared__ int      s_prefix[10], s_n, s_mstop, s_done;

    uint64_t* s_k = s_bm;                   // raw keys
    uint64_t* s_g = s_bm + 1024;            // grouped by bucket

    if (tid < NB)                    s_bcnt[tid] = 0;
    else if (tid < 2 * NB)           s_bcur[tid - NB] = 0;
    else if (tid == 2 * NB)        { s_cnt = 0; s_fp = 0x7FFFFFFF; }
    __syncthreads();

    // ---- 1. compact own column: DEPTH-2 PIPELINED loads, ballot push ----
    {
        const int lid = tid & 63;
        float vcur  = confb[(size_t)tid * C_CLASSES];
        float vnext = confb[(size_t)(tid + 1024) * C_CLASSES];
        #pragma unroll
        for (int r = 0; r < 9; ++r) {
            float v = vcur;
            vcur = vnext;
            // issue load r+2 (2 in flight max); r+2==8 is the guarded tail
            if (r + 2 <= 7) {
                vnext = confb[(size_t)(tid + ((r + 2) << 10)) * C_CLASSES];
            } else if (r + 2 == 8) {
                int pn = tid + 8192;
                vnext = (pn < P_PRIORS) ? confb[(size_t)pn * C_CLASSES] : 0.0f;
            } else {
                vnext = 0.0f;
            }
            int p = tid + (r << 10);
            bool pass = v > CONF_T;          // OOB tail loaded as 0.0f -> false
            uint64_t mask = __ballot(pass);
            if (mask != 0) {
                int leader = (int)__ffsll((unsigned long long)mask) - 1;
                int base = 0;
                if (lid == leader) {
                    base = atomicAdd(&s_cnt, __popcll(mask));  // 1 atomic/wave
                    atomicMin(&s_fp, p);     // leader = lowest lane = lowest p
                }
                base = __shfl(base, leader, 64);
                if (pass) {
                    int pos = base + __popcll(mask & ((1ull << lid) - 1ull));
                    if (pos < 1024) s_k[pos] = pack_key(v, p);
                }
            }
        }
    }
    __syncthreads();
    int cnt = s_cnt; if (cnt > 1024) cnt = 1024;
    if (cnt == 0) {
        for (int k = tid; k < TOPK * 5; k += 1024) o[k] = 0.0f;
        return;
    }

    // ---- 2. bucket histogram ----
    for (int t = tid; t < cnt; t += 1024)
        atomicAdd(&s_bcnt[bucket_of(s_k[t])], 1);
    __syncthreads();

    // ---- 3a. bucket offsets: wave-0 reversed shuffle scan ----
    if (tid < 64) {
        int c = s_bcnt[63 - tid];
        int incl = c;
        #pragma unroll
        for (int d = 1; d < 64; d <<= 1) {
            int u = __shfl_up(incl, d, 64);
            if (tid >= d) incl += u;
        }
        s_boff[63 - tid] = incl - c;        // sum of counts of buckets > bb
    }
    __syncthreads();

    // ---- 3b. scatter grouped-by-bucket ----
    for (int t = tid; t < cnt; t += 1024) {
        uint64_t kt = s_k[t];
        int bb = bucket_of(kt);
        s_g[s_boff[bb] + atomicAdd(&s_bcur[bb], 1)] = kt;
    }
    __syncthreads();

    // ---- 3c. WAVE-PER-BUCKET rank FUSED with gather: write score/box/area
    // at rank r directly (keys unique => ranks unique => exact stable order).
    const int M = cnt < MCAND ? cnt : MCAND;
    {
        const int wid = tid >> 6, lid = tid & 63;
        for (int bb = wid; bb < NB; bb += 16) {
            int st = s_boff[bb], n = s_bcnt[bb];
            for (int e = lid; e < n; e += 64) {
                uint64_t kq = s_g[st + e];
                int r = st;
                for (int q = 0; q < n; ++q)
                    r += (s_g[st + q] > kq) ? 1 : 0;   // same addr all lanes
                if (r < MCAND) {
                    int p = (int)(~(uint32_t)kq);
                    s_ssc[r]  = __uint_as_float((uint32_t)(kq >> 32));
                    float4 bx = loc4[p];               // hidden under rank loop
                    s_jb[r]   = bx;
                    s_area[r] = (bx.z - bx.x) * (bx.w - bx.y);
                }
            }
        }
    }
    // pad region (independent of rank writes)
    for (int i = M + tid; i < 640; i += 1024) {
        s_jb[i]   = make_float4(INFINITY, INFINITY, INFINITY, INFINITY);
        s_area[i] = INFINITY;
    }
    const int fp = s_fp;
    __syncthreads();                        // key data dead; s_bm -> bitmask

    const int kmax = (M + 63) >> 6;
    const int kcap = kmax < KCAP ? kmax : KCAP; // words consumed when mstop<=256

    // ---- 4+5. ROLE-SPLIT rounds: wave 0 scans chunk c; waves 1-15 build
    // chunk c+1. Round wall = max(scan, iou). Early exit at 200 keeps.
    // Only words [c, kcap) computed: supp words >= kcap accumulate garbage but
    // are consumed only if mstop > 64*kcap -> handled by the fallback below.
    {
        const int wid = tid >> 6, lid = tid & 63;
        const int w   = (lid < 10) ? lid : 0;         // wave-0 word slot
        uint64_t supp = 0;
        int kept = 0, mstop = M;
        const int nch = kcap;               // scannable chunks (rows < 64*kcap)

        iou_chunk16(0, wid, lid, M, kcap, s_jb, s_area, s_bm);  // 16-wave prologue
        __syncthreads();

        for (int c = 0; c < nch; ++c) {
            if (wid == 0) {
                // ---- scan chunk c (serial, 8-ahead LDS prefetch) ----
                const int ibeg = c << 6;
                const int iend = min(ibeg + 64, M);
                uint64_t rb[8];
                #pragma unroll
                for (int d = 0; d < 8; ++d) {
                    int i = ibeg + d;
                    rb[d] = (i < iend) ? s_bm[(size_t)i * 10 + w] : 0;
                }
                for (int i = ibeg; i < iend; ++i) {
                    uint64_t row = rb[i & 7];
                    if (w < c) row = 0;               // sub-diagonal words unwritten
                    int ip = i + 8;
                    rb[i & 7] = (ip < iend) ? s_bm[(size_t)ip * 10 + w] : 0;
                    bool mybit = (w == c) && ((supp >> (i & 63)) & 1ull);
                    if (!__any((int)mybit)) {         // not suppressed -> keep
                        supp |= row;
                        if (++kept == TOPK) { mstop = i + 1; break; }
                    }
                }
                if (lid == 0) s_done = (kept >= TOPK) ? 1 : 0;
            } else if (c + 1 < nch) {
                iou_rows15(c + 1, wid, lid, M, kcap, s_jb, s_area, s_bm);
            }
            __syncthreads();
            if (s_done) break;                        // uniform after barrier
        }
        if (wid == 0) {
            if (lid < 10) s_suppw[lid] = supp;
            if (lid == 0) s_mstop = mstop;
        }
    }
    __syncthreads();

    // ---- 5b. RARE fallback: scan exhausted rows < 64*kcap with kept < 200
    // and M beyond -> full-extent recompute + full rescan (never on this data).
    if (s_done == 0 && M > (KCAP << 6)) {
        const int wid = tid >> 6, lid = tid & 63;
        for (int i = wid; i < M; i += 16) {
            float4 bi = s_jb[i];
            float  ai = s_area[i];
            const int k0 = i >> 6;
            uint64_t diag = ((i & 63) == 63) ? 0ull : (~0ull << ((i & 63) + 1));
            uint64_t myw = 0;
            for (int k = k0; k < kmax; ++k) {
                float4 bj = s_jb[(k << 6) + lid];
                float  aj = s_area[(k << 6) + lid];
                float xx1 = fmaxf(bi.x, bj.x);
                float yy1 = fmaxf(bi.y, bj.y);
                float xx2 = fminf(bi.z, bj.z);
                float yy2 = fminf(bi.w, bj.w);
                float ww  = fmaxf(xx2 - xx1, 0.0f);
                float hh  = fmaxf(yy2 - yy1, 0.0f);
                float inter = ww * hh;
                float den   = (ai + aj) - inter;
                float iou   = inter / den;
                uint64_t m = __ballot(iou > NMS_T);
                if (k == k0) m &= diag;
                myw = (lid == k) ? m : myw;
            }
            if (lid >= k0 && lid < kmax) s_bm[(size_t)i * 10 + lid] = myw;
        }
        __syncthreads();
        if (tid < 64) {                     // full serial rescan (proven form)
            const int w = (tid < 10) ? tid : 0;
            uint64_t supp = 0;
            int kept = 0, ms = M;
            for (int i = 0; i < M; ++i) {
                uint64_t row = s_bm[(size_t)i * 10 + w];
                if (w < (i >> 6)) row = 0;
                unsigned part  = (unsigned)(supp >> (i & 32));
                unsigned wordv = (unsigned)__builtin_amdgcn_readlane((int)part, i >> 6);
                if (!((wordv >> (i & 31)) & 1u)) {
                    supp |= row;
                    if (++kept == TOPK) { ms = i + 1; break; }
                }
            }
            if (tid < 10) s_suppw[tid] = supp;
            if (tid == 0) s_mstop = ms;
        }
        __syncthreads();
    }

    if (tid == 0) {
        const int Me = s_mstop;
        int total = 0;
        for (int w = 0; w < 10; ++w) {
            uint64_t kw = 0;
            int rem = Me - (w << 6);
            if (rem > 0) {
                uint64_t vm = (rem >= 64) ? ~0ull : ((1ull << rem) - 1ull);
                kw = (~s_suppw[w]) & vm;
            }
            s_keepw[w]  = kw;
            s_prefix[w] = total;
            total += __popcll(kw);
        }
        s_n = total < TOPK ? total : TOPK;
    }
    __syncthreads();

    // ---- 6. output ----
    const int n  = s_n;
    const int Me = s_mstop;
    float4 fbox = loc4[fp];
    for (int k = tid; k < TOPK; k += 1024) {
        if (k >= n) {
            o[k * 5 + 0] = 0.0f;
            o[k * 5 + 1] = fbox.x; o[k * 5 + 2] = fbox.y;
            o[k * 5 + 3] = fbox.z; o[k * 5 + 4] = fbox.w;
        }
    }
    for (int t = tid; t < Me; t += 1024) {
        uint64_t kw = s_keepw[t >> 6];
        if ((kw >> (t & 63)) & 1ull) {
            int r = s_prefix[t >> 6] + __popcll(kw & ((1ull << (t & 63)) - 1ull));
            if (r < TOPK) {
                float4 bx = s_jb[t];
                o[r * 5 + 0] = s_ssc[t];
                o[r * 5 + 1] = bx.x; o[r * 5 + 2] = bx.y;
                o[r * 5 + 3] = bx.z; o[r * 5 + 4] = bx.w;
            }
        }
    }
}

extern "C" void kernel_launch(void* const* d_in, const int* in_sizes, int n_in,
                              void* d_out, int out_size, void* d_ws, size_t ws_size,
                              hipStream_t stream) {
    const float* loc  = (const float*)d_in[0];   // [8, 8732, 4]
    const float* conf = (const float*)d_in[1];   // [8, 8732, 21]
    float* out = (float*)d_out;                  // [8, 21, 200, 5]
    (void)d_ws; (void)ws_size;

    detect_one<<<dim3(B_BATCH * C_CLASSES), dim3(1024), 0, stream>>>(loc, conf, out);
}